// Round 11
// baseline (1387.945 us; speedup 1.0000x reference)
//
#include <hip/hip_runtime.h>
#include <hip/hip_fp16.h>
#include <cstdint>
#include <cstddef>

#define N_NODES 100000
#define N_EDGES 1600000
#define H 128
#define L_LAYERS 5
#define G_GRAPHS 128
#define OUT_F 128
#define BN_EPS 1e-5f
#define SCAN_BLOCKS 98   // ceil(100000/1024)

typedef _Float16 half8_t __attribute__((ext_vector_type(8)));
typedef _Float16 h2_t __attribute__((ext_vector_type(2)));
typedef float floatx4 __attribute__((ext_vector_type(4)));

__device__ __forceinline__ float frelu(float x) { return fmaxf(x, 0.0f); }

// ================= preprocessing =================

__global__ void count_kernel(const int* __restrict__ erow, const int* __restrict__ ecol,
                             int* __restrict__ degcnt, int* __restrict__ hist) {
    int e = blockIdx.x * 256 + threadIdx.x;  // E divisible by 256
    atomicAdd(&degcnt[erow[e]], 1);
    atomicAdd(&hist[ecol[e]], 1);
}

__global__ void finish_deg(const int* __restrict__ degcnt, float* __restrict__ dis,
                           float* __restrict__ invdeg) {
    int i = blockIdx.x * 256 + threadIdx.x;
    if (i < N_NODES) {
        float d = (float)degcnt[i] + 1.0f;
        dis[i] = rsqrtf(d);
        invdeg[i] = 1.0f / d;
    }
}

// ---- two-level scan ----
__global__ __launch_bounds__(1024) void scan_part(const int* __restrict__ hist,
                                                  int* __restrict__ rowptr,
                                                  int* __restrict__ blocksum) {
    int t = threadIdx.x;
    int i = blockIdx.x * 1024 + t;
    int orig = (i < N_NODES) ? hist[i] : 0;
    int v = orig;
#pragma unroll
    for (int off = 1; off < 64; off <<= 1) {
        int u = __shfl_up(v, off);
        if ((t & 63) >= off) v += u;
    }
    __shared__ int wsum[16];
    int wid = t >> 6;
    if ((t & 63) == 63) wsum[wid] = v;
    __syncthreads();
    int woff = 0;
#pragma unroll
    for (int w = 0; w < 16; w++)
        if (w < wid) woff += wsum[w];
    int incl = v + woff;
    if (i < N_NODES) rowptr[i] = incl - orig;
    if (t == 1023) blocksum[blockIdx.x] = incl;
}

__global__ __launch_bounds__(128) void scan_block(const int* __restrict__ blocksum,
                                                  int* __restrict__ blockoff,
                                                  int* __restrict__ rowptr) {
    int t = threadIdx.x;
    int orig = (t < SCAN_BLOCKS) ? blocksum[t] : 0;
    int v = orig;
#pragma unroll
    for (int off = 1; off < 64; off <<= 1) {
        int u = __shfl_up(v, off);
        if ((t & 63) >= off) v += u;
    }
    __shared__ int w0;
    if (t == 63) w0 = v;
    __syncthreads();
    if (t >= 64) v += w0;
    if (t < SCAN_BLOCKS) blockoff[t] = v - orig;
    if (t == 0) rowptr[N_NODES] = N_EDGES;
}

__global__ __launch_bounds__(1024) void scan_add(int* __restrict__ rowptr,
                                                 const int* __restrict__ blockoff,
                                                 int* __restrict__ cursor) {
    int i = blockIdx.x * 1024 + threadIdx.x;
    if (i < N_NODES) {
        int v = rowptr[i] + blockoff[blockIdx.x];
        rowptr[i] = v;
        cursor[i] = v;
    }
}

// permute edge payloads into col-sorted order, fp16-compressed:
//   eah[pos] = half8 {a0..a6, norm}   rows[pos] = row
__global__ void scatter_kernel(const int* __restrict__ erow, const int* __restrict__ ecol,
                               const float* __restrict__ ea, const float* __restrict__ dis,
                               int* __restrict__ cursor,
                               half8_t* __restrict__ eah, int* __restrict__ rows) {
    int e = blockIdx.x * 256 + threadIdx.x;
    int c = ecol[e];
    int r = erow[e];
    float nrm = dis[r] * dis[c];
    int pos = atomicAdd(&cursor[c], 1);
    const float* p = ea + (size_t)e * 7;
    half8_t v;
    v[0] = (_Float16)p[0]; v[1] = (_Float16)p[1]; v[2] = (_Float16)p[2];
    v[3] = (_Float16)p[3]; v[4] = (_Float16)p[4]; v[5] = (_Float16)p[5];
    v[6] = (_Float16)p[6]; v[7] = (_Float16)nrm;
    eah[pos] = v;
    rows[pos] = r;
}

// ================= xl = act(h) @ W + b  via MFMA f16 =================
__global__ __launch_bounds__(256) void gemm_xl(const _Float16* __restrict__ hsrc,
                                               const int* __restrict__ xidx,
                                               const float* __restrict__ nemb,
                                               const float* __restrict__ colsum_p,
                                               const float* __restrict__ colsumsq_p,
                                               const float* __restrict__ gamma_p,
                                               const float* __restrict__ beta_p,
                                               const float* __restrict__ Wl,
                                               const float* __restrict__ bl,
                                               _Float16* __restrict__ xlo, int mode) {
    __shared__ half8_t sB[2048];          // [ct][ks][lane] fragments, 32 KB
    __shared__ float sScale[H], sShift[H];
    int t = threadIdx.x;
    if (mode == 1 && t < H) {
        float mean = colsum_p[t] * (1.0f / N_NODES);
        float var = colsumsq_p[t] * (1.0f / N_NODES) - mean * mean;
        float s = gamma_p[t] * rsqrtf(var + BN_EPS);
        sScale[t] = s;
        sShift[t] = beta_p[t] - mean * s;
    }
    // stage W as B-fragments
    for (int idx = t; idx < 2048; idx += 256) {
        int ct = idx >> 8;
        int ks = (idx >> 6) & 3;
        int ln = idx & 63;
        int kbase = ks * 32 + (ln >> 4) * 8;
        int c = ct * 16 + (ln & 15);
        half8_t v;
#pragma unroll
        for (int i = 0; i < 8; i++)
            v[i] = (_Float16)Wl[(size_t)(kbase + i) * H + c];
        sB[idx] = v;
    }
    __syncthreads();

    int w = t >> 6, lane = t & 63;
    int lq = lane >> 4, lr = lane & 15;
    int rbase = blockIdx.x * 128 + w * 32;

    floatx4 acc[2][8];
#pragma unroll
    for (int rt = 0; rt < 2; rt++)
#pragma unroll
        for (int ct = 0; ct < 8; ct++) acc[rt][ct] = (floatx4)0.0f;

    float bias[8];
#pragma unroll
    for (int ct = 0; ct < 8; ct++) bias[ct] = bl[ct * 16 + lr];

    int arow[2], xv[2];
#pragma unroll
    for (int rt = 0; rt < 2; rt++) {
        int row = rbase + rt * 16 + lr;
        if (row > N_NODES - 1) row = N_NODES - 1;
        arow[rt] = row;
        if (mode == 0) xv[rt] = xidx[row];
    }

    for (int ks = 0; ks < 4; ks++) {
        int k0 = ks * 32 + lq * 8;
        half8_t a[2];
#pragma unroll
        for (int rt = 0; rt < 2; rt++) {
            float f[8];
            if (mode == 0) {
                const float* p = nemb + (size_t)xv[rt] * H + k0;
                float4 u0 = *(const float4*)p;
                float4 u1 = *(const float4*)(p + 4);
                f[0] = u0.x; f[1] = u0.y; f[2] = u0.z; f[3] = u0.w;
                f[4] = u1.x; f[5] = u1.y; f[6] = u1.z; f[7] = u1.w;
            } else {
                half8_t u = *(const half8_t*)(hsrc + (size_t)arow[rt] * H + k0);
#pragma unroll
                for (int i = 0; i < 8; i++)
                    f[i] = frelu((float)u[i] * sScale[k0 + i] + sShift[k0 + i]);
            }
            half8_t av;
#pragma unroll
            for (int i = 0; i < 8; i++) av[i] = (_Float16)f[i];
            a[rt] = av;
        }
#pragma unroll
        for (int ct = 0; ct < 8; ct++) {
            half8_t bf = sB[(ct * 4 + ks) * 64 + lane];
            acc[0][ct] = __builtin_amdgcn_mfma_f32_16x16x32_f16(a[0], bf, acc[0][ct], 0, 0, 0);
            acc[1][ct] = __builtin_amdgcn_mfma_f32_16x16x32_f16(a[1], bf, acc[1][ct], 0, 0, 0);
        }
    }

#pragma unroll
    for (int rt = 0; rt < 2; rt++)
#pragma unroll
        for (int ct = 0; ct < 8; ct++)
#pragma unroll
            for (int r = 0; r < 4; r++) {
                int row = rbase + rt * 16 + lq * 4 + r;
                if (row < N_NODES) {
                    _Float16 hv = (_Float16)(acc[rt][ct][r] + bias[ct]);
                    __builtin_nontemporal_store(hv, &xlo[(size_t)row * H + ct * 16 + lr]);
                }
            }
}

// ================= gather aggregation + BN stats =================
// wave per node (strided); lane owns cols {2*lane, 2*lane+1}; xl gathered as
// h2_t (cached); payload NT-loads, hpre NT-store (keep L2 for xl gathers).
// MLP in packed fp16 (v_pk_fma_f16), fp32 only for norm-scaled accumulate.
__global__ __launch_bounds__(256) void agg_kernel(
    const int* __restrict__ rowptr, const half8_t* __restrict__ eah,
    const int* __restrict__ rows, const h2_t* __restrict__ xld,
    const float* __restrict__ invdeg, const float* __restrict__ rootl,
    const float* __restrict__ Wel, const float* __restrict__ bel,
    h2_t* __restrict__ hpd, float* __restrict__ colsum,
    float* __restrict__ colsumsq) {
    int t = threadIdx.x;
    int lane = t & 63, wv = t >> 6;
    int c0 = lane * 2;
    h2_t W20, W21, W22, W23, W24, W25, W26, be2;
    W20[0] = (_Float16)Wel[0 * H + c0]; W20[1] = (_Float16)Wel[0 * H + c0 + 1];
    W21[0] = (_Float16)Wel[1 * H + c0]; W21[1] = (_Float16)Wel[1 * H + c0 + 1];
    W22[0] = (_Float16)Wel[2 * H + c0]; W22[1] = (_Float16)Wel[2 * H + c0 + 1];
    W23[0] = (_Float16)Wel[3 * H + c0]; W23[1] = (_Float16)Wel[3 * H + c0 + 1];
    W24[0] = (_Float16)Wel[4 * H + c0]; W24[1] = (_Float16)Wel[4 * H + c0 + 1];
    W25[0] = (_Float16)Wel[5 * H + c0]; W25[1] = (_Float16)Wel[5 * H + c0 + 1];
    W26[0] = (_Float16)Wel[6 * H + c0]; W26[1] = (_Float16)Wel[6 * H + c0 + 1];
    be2[0] = (_Float16)bel[c0]; be2[1] = (_Float16)bel[c0 + 1];
    h2_t zero2;
    zero2[0] = (_Float16)0.0f; zero2[1] = (_Float16)0.0f;
    float rt0 = rootl[c0], rt1 = rootl[c0 + 1];
    float s0 = 0, s1 = 0, q0 = 0, q1 = 0;

#define MLP_BODY(PV, XG)                                                     \
    {                                                                        \
        h2_t m_ = be2;                                                       \
        m_ += (PV)[0] * W20;                                                 \
        m_ += (PV)[1] * W21;                                                 \
        m_ += (PV)[2] * W22;                                                 \
        m_ += (PV)[3] * W23;                                                 \
        m_ += (PV)[4] * W24;                                                 \
        m_ += (PV)[5] * W25;                                                 \
        m_ += (PV)[6] * W26;                                                 \
        h2_t sm_ = __builtin_elementwise_max((XG) + m_, zero2);              \
        float nrm_ = (float)(PV)[7];                                         \
        a0 = fmaf((float)sm_[0], nrm_, a0);                                  \
        a1 = fmaf((float)sm_[1], nrm_, a1);                                  \
    }

    for (int n_ = blockIdx.x * 4 + wv; n_ < N_NODES; n_ += gridDim.x * 4) {
        int n = __builtin_amdgcn_readfirstlane(n_);
        int jb = __builtin_amdgcn_readfirstlane(rowptr[n]);
        int je = __builtin_amdgcn_readfirstlane(rowptr[n + 1]);
        float a0 = 0, a1 = 0;
        int j = jb;
        for (; j + 16 <= je; j += 16) {
            int rr[16];
#pragma unroll
            for (int i = 0; i < 16; i++) rr[i] = rows[j + i];
            h2_t g[16];
#pragma unroll
            for (int i = 0; i < 16; i++) g[i] = xld[(size_t)rr[i] * 64 + lane];
#pragma unroll
            for (int i = 0; i < 16; i++) {
                half8_t pv = __builtin_nontemporal_load(&eah[j + i]);
                MLP_BODY(pv, g[i]);
            }
        }
        if (j + 8 <= je) {
            int rr[8];
#pragma unroll
            for (int i = 0; i < 8; i++) rr[i] = rows[j + i];
            h2_t g[8];
#pragma unroll
            for (int i = 0; i < 8; i++) g[i] = xld[(size_t)rr[i] * 64 + lane];
#pragma unroll
            for (int i = 0; i < 8; i++) {
                half8_t pv = __builtin_nontemporal_load(&eah[j + i]);
                MLP_BODY(pv, g[i]);
            }
            j += 8;
        }
        if (j + 4 <= je) {
            int rr[4];
#pragma unroll
            for (int i = 0; i < 4; i++) rr[i] = rows[j + i];
            h2_t g[4];
#pragma unroll
            for (int i = 0; i < 4; i++) g[i] = xld[(size_t)rr[i] * 64 + lane];
#pragma unroll
            for (int i = 0; i < 4; i++) {
                half8_t pv = __builtin_nontemporal_load(&eah[j + i]);
                MLP_BODY(pv, g[i]);
            }
            j += 4;
        }
        for (; j < je; j++) {
            int r_ = rows[j];
            h2_t g_ = xld[(size_t)r_ * 64 + lane];
            half8_t pv = __builtin_nontemporal_load(&eah[j]);
            MLP_BODY(pv, g_);
        }
        h2_t xn2 = xld[(size_t)n * 64 + lane];
        float id = invdeg[n];
        float p0 = a0 + frelu((float)xn2[0] + rt0) * id;
        float p1 = a1 + frelu((float)xn2[1] + rt1) * id;
        h2_t hp;
        hp[0] = (_Float16)p0; hp[1] = (_Float16)p1;
        __builtin_nontemporal_store(hp, &hpd[(size_t)n * 64 + lane]);
        s0 += p0; s1 += p1;
        q0 = fmaf(p0, p0, q0); q1 = fmaf(p1, p1, q1);
    }
#undef MLP_BODY

    __shared__ float red[4][H];
    red[wv][c0] = s0; red[wv][c0 + 1] = s1;
    __syncthreads();
    if (wv == 0) {
        float t0 = red[0][c0] + red[1][c0] + red[2][c0] + red[3][c0];
        float t1 = red[0][c0 + 1] + red[1][c0 + 1] + red[2][c0 + 1] + red[3][c0 + 1];
        unsafeAtomicAdd(&colsum[c0], t0);
        unsafeAtomicAdd(&colsum[c0 + 1], t1);
    }
    __syncthreads();
    red[wv][c0] = q0; red[wv][c0 + 1] = q1;
    __syncthreads();
    if (wv == 0) {
        float t0 = red[0][c0] + red[1][c0] + red[2][c0] + red[3][c0];
        float t1 = red[0][c0 + 1] + red[1][c0 + 1] + red[2][c0 + 1] + red[3][c0 + 1];
        unsafeAtomicAdd(&colsumsq[c0], t0);
        unsafeAtomicAdd(&colsumsq[c0 + 1], t1);
    }
}

// ================= pool (applies final BN in-kernel, fp16 input) =================
__global__ __launch_bounds__(256) void pool_kernel(const h2_t* __restrict__ hh,
                                                   const int* __restrict__ batch,
                                                   const float* __restrict__ colsum_p,
                                                   const float* __restrict__ colsumsq_p,
                                                   const float* __restrict__ gamma_p,
                                                   const float* __restrict__ beta_p,
                                                   float* __restrict__ pooled,
                                                   float* __restrict__ cnt) {
    __shared__ float sScale[H], sShift[H];
    int t = threadIdx.x;
    if (t < H) {
        float mean = colsum_p[t] * (1.0f / N_NODES);
        float var = colsumsq_p[t] * (1.0f / N_NODES) - mean * mean;
        float s = gamma_p[t] * rsqrtf(var + BN_EPS);
        sScale[t] = s;
        sShift[t] = beta_p[t] - mean * s;
    }
    __syncthreads();
    int cg = t & 63, rg = t >> 6;
    int c0 = cg * 2;
    float sc0 = sScale[c0], sc1 = sScale[c0 + 1];
    float sh0 = sShift[c0], sh1 = sShift[c0 + 1];
    int per = (N_NODES + gridDim.x - 1) / gridDim.x;
    int rstart = blockIdx.x * per;
    int rend = min(rstart + per, N_NODES);
    float a0 = 0, a1 = 0, runc = 0.0f;
    int cur = -1;
    for (int rowi = rstart + rg; rowi < rend; rowi += 4) {
        int g = batch[rowi];
        if (g != cur) {
            if (cur >= 0) {
                unsafeAtomicAdd(&pooled[(size_t)cur * H + c0 + 0], a0);
                unsafeAtomicAdd(&pooled[(size_t)cur * H + c0 + 1], a1);
                if (cg == 0) unsafeAtomicAdd(&cnt[cur], runc);
            }
            cur = g; a0 = 0; a1 = 0; runc = 0.0f;
        }
        h2_t v = hh[(size_t)rowi * 64 + cg];
        a0 += (float)v[0] * sc0 + sh0;
        a1 += (float)v[1] * sc1 + sh1;
        runc += 1.0f;
    }
    if (cur >= 0) {
        unsafeAtomicAdd(&pooled[(size_t)cur * H + c0 + 0], a0);
        unsafeAtomicAdd(&pooled[(size_t)cur * H + c0 + 1], a1);
        if (cg == 0) unsafeAtomicAdd(&cnt[cur], runc);
    }
}

__global__ __launch_bounds__(128) void final_gemm(const float* __restrict__ pooled,
                                                  const float* __restrict__ cnt,
                                                  const float* __restrict__ Wout,
                                                  const float* __restrict__ bout,
                                                  float* __restrict__ out) {
    __shared__ float sh[H];
    int g = blockIdx.x;
    int o = threadIdx.x;
    float c = fmaxf(cnt[g], 1.0f);
    sh[o] = pooled[(size_t)g * H + o] / c;
    __syncthreads();
    float acc = bout[o];
#pragma unroll 8
    for (int k = 0; k < H; k++) acc += sh[k] * Wout[(size_t)k * OUT_F + o];
    out[(size_t)g * OUT_F + o] = acc;
}

extern "C" void kernel_launch(void* const* d_in, const int* in_sizes, int n_in,
                              void* d_out, int out_size, void* d_ws, size_t ws_size,
                              hipStream_t stream) {
    const int*   x     = (const int*)d_in[0];
    const int*   ei    = (const int*)d_in[1];
    const float* ea    = (const float*)d_in[2];
    const int*   batch = (const int*)d_in[3];
    const float* nemb  = (const float*)d_in[4];
    const float* W     = (const float*)d_in[5];
    const float* b     = (const float*)d_in[6];
    const float* We    = (const float*)d_in[7];
    const float* be    = (const float*)d_in[8];
    const float* root  = (const float*)d_in[9];
    const float* gamma = (const float*)d_in[10];
    const float* beta  = (const float*)d_in[11];
    const float* Wout  = (const float*)d_in[12];
    const float* bout  = (const float*)d_in[13];
    float* out = (float*)d_out;

    const int* erow = ei;
    const int* ecol = ei + N_EDGES;

    float* ws = (float*)d_ws;
    size_t NH = (size_t)N_NODES * H;
    half8_t* eah  = (half8_t*)ws;                        // E half8 (fp16 payload)
    int*   rows   = (int*)(eah + N_EDGES);               // E ints
    float* hslot  = (float*)(rows + N_EDGES);            // NH/2 floats (fp16 hpre)
    _Float16* hpreh = (_Float16*)hslot;
    float* xslot  = hslot + NH / 2;                      // NH/2 floats (fp16 xl)
    _Float16* xlh = (_Float16*)xslot;
    int*   rowptr = (int*)(xslot + NH / 2);              // N+1 (+pad)
    float* dis    = (float*)(rowptr + N_NODES + 4);
    float* invdeg = dis + N_NODES;
    float* colsumAll = invdeg + N_NODES;                 // L*2*H floats
    float* pooled   = colsumAll + (size_t)L_LAYERS * 2 * H;
    float* cnt      = pooled + (size_t)G_GRAPHS * H;
    int*   blocksum = (int*)(cnt + G_GRAPHS);            // 128
    int*   blockoff = blocksum + 128;                    // 128

    // preprocessing temps alias into hpre region (hpre first written in layer 0 agg)
    int* degcnt = (int*)hslot;
    int* hist   = degcnt + N_NODES;
    int* cursor = hist + N_NODES;

    hipMemsetAsync(degcnt, 0, 2 * N_NODES * sizeof(int), stream);
    hipMemsetAsync(colsumAll, 0, (size_t)L_LAYERS * 2 * H * sizeof(float), stream);
    hipLaunchKernelGGL(count_kernel, dim3(N_EDGES / 256), dim3(256), 0, stream,
                       erow, ecol, degcnt, hist);
    hipLaunchKernelGGL(finish_deg, dim3((N_NODES + 255) / 256), dim3(256), 0, stream,
                       degcnt, dis, invdeg);
    hipLaunchKernelGGL(scan_part, dim3(SCAN_BLOCKS), dim3(1024), 0, stream,
                       hist, rowptr, blocksum);
    hipLaunchKernelGGL(scan_block, dim3(1), dim3(128), 0, stream,
                       blocksum, blockoff, rowptr);
    hipLaunchKernelGGL(scan_add, dim3(SCAN_BLOCKS), dim3(1024), 0, stream,
                       rowptr, blockoff, cursor);
    hipLaunchKernelGGL(scatter_kernel, dim3(N_EDGES / 256), dim3(256), 0, stream,
                       erow, ecol, ea, dis, cursor, eah, rows);

    for (int l = 0; l < L_LAYERS; l++) {
        const float* cs_prev = colsumAll + (size_t)(l - 1) * 2 * H;  // unused when l==0
        hipLaunchKernelGGL(gemm_xl, dim3((N_NODES + 127) / 128), dim3(256), 0, stream,
                           hpreh, x, nemb,
                           (l == 0) ? colsumAll : cs_prev,
                           (l == 0) ? colsumAll : cs_prev + H,
                           gamma + (size_t)(l ? l - 1 : 0) * H,
                           beta + (size_t)(l ? l - 1 : 0) * H,
                           W + (size_t)l * H * H, b + (size_t)l * H, xlh,
                           (l == 0) ? 0 : 1);
        float* cs = colsumAll + (size_t)l * 2 * H;
        hipLaunchKernelGGL(agg_kernel, dim3(2048), dim3(256), 0, stream,
                           rowptr, eah, rows, (const h2_t*)xlh, invdeg,
                           root + (size_t)l * H, We + (size_t)l * 7 * H, be + (size_t)l * H,
                           (h2_t*)hpreh, cs, cs + H);
    }

    hipMemsetAsync(pooled, 0, ((size_t)G_GRAPHS * H + G_GRAPHS) * sizeof(float), stream);
    {
        const float* cs4 = colsumAll + (size_t)(L_LAYERS - 1) * 2 * H;
        hipLaunchKernelGGL(pool_kernel, dim3(256), dim3(256), 0, stream,
                           (const h2_t*)hpreh, batch, cs4, cs4 + H,
                           gamma + (size_t)(L_LAYERS - 1) * H,
                           beta + (size_t)(L_LAYERS - 1) * H, pooled, cnt);
    }
    hipLaunchKernelGGL(final_gemm, dim3(G_GRAPHS), dim3(OUT_F), 0, stream,
                       pooled, cnt, Wout, bout, out);
}

// Round 13
// 1338.119 us; speedup vs baseline: 1.0372x; 1.0372x over previous
//
#include <hip/hip_runtime.h>
#include <hip/hip_fp16.h>
#include <cstdint>
#include <cstddef>

#define N_NODES 100000
#define N_EDGES 1600000
#define H 128
#define L_LAYERS 5
#define G_GRAPHS 128
#define OUT_F 128
#define BN_EPS 1e-5f
#define SCAN_BLOCKS 98   // ceil(100000/1024)

typedef _Float16 half8_t __attribute__((ext_vector_type(8)));
typedef _Float16 h2_t __attribute__((ext_vector_type(2)));
typedef float floatx4 __attribute__((ext_vector_type(4)));

__device__ __forceinline__ float frelu(float x) { return fmaxf(x, 0.0f); }

// ================= preprocessing =================

__global__ void count_kernel(const int* __restrict__ erow, const int* __restrict__ ecol,
                             int* __restrict__ degcnt, int* __restrict__ hist) {
    int e = blockIdx.x * 256 + threadIdx.x;  // E divisible by 256
    atomicAdd(&degcnt[erow[e]], 1);
    atomicAdd(&hist[ecol[e]], 1);
}

__global__ void finish_deg(const int* __restrict__ degcnt, float* __restrict__ dis,
                           float* __restrict__ invdeg) {
    int i = blockIdx.x * 256 + threadIdx.x;
    if (i < N_NODES) {
        float d = (float)degcnt[i] + 1.0f;
        dis[i] = rsqrtf(d);
        invdeg[i] = 1.0f / d;
    }
}

// ---- two-level scan ----
__global__ __launch_bounds__(1024) void scan_part(const int* __restrict__ hist,
                                                  int* __restrict__ rowptr,
                                                  int* __restrict__ blocksum) {
    int t = threadIdx.x;
    int i = blockIdx.x * 1024 + t;
    int orig = (i < N_NODES) ? hist[i] : 0;
    int v = orig;
#pragma unroll
    for (int off = 1; off < 64; off <<= 1) {
        int u = __shfl_up(v, off);
        if ((t & 63) >= off) v += u;
    }
    __shared__ int wsum[16];
    int wid = t >> 6;
    if ((t & 63) == 63) wsum[wid] = v;
    __syncthreads();
    int woff = 0;
#pragma unroll
    for (int w = 0; w < 16; w++)
        if (w < wid) woff += wsum[w];
    int incl = v + woff;
    if (i < N_NODES) rowptr[i] = incl - orig;
    if (t == 1023) blocksum[blockIdx.x] = incl;
}

__global__ __launch_bounds__(128) void scan_block(const int* __restrict__ blocksum,
                                                  int* __restrict__ blockoff,
                                                  int* __restrict__ rowptr) {
    int t = threadIdx.x;
    int orig = (t < SCAN_BLOCKS) ? blocksum[t] : 0;
    int v = orig;
#pragma unroll
    for (int off = 1; off < 64; off <<= 1) {
        int u = __shfl_up(v, off);
        if ((t & 63) >= off) v += u;
    }
    __shared__ int w0;
    if (t == 63) w0 = v;
    __syncthreads();
    if (t >= 64) v += w0;
    if (t < SCAN_BLOCKS) blockoff[t] = v - orig;
    if (t == 0) rowptr[N_NODES] = N_EDGES;
}

__global__ __launch_bounds__(1024) void scan_add(int* __restrict__ rowptr,
                                                 const int* __restrict__ blockoff,
                                                 int* __restrict__ cursor) {
    int i = blockIdx.x * 1024 + threadIdx.x;
    if (i < N_NODES) {
        int v = rowptr[i] + blockoff[blockIdx.x];
        rowptr[i] = v;
        cursor[i] = v;
    }
}

// permute edge payloads into col-sorted order, fp16-compressed:
//   eah[pos] = half8 {a0..a6, norm}   rows[pos] = row
__global__ void scatter_kernel(const int* __restrict__ erow, const int* __restrict__ ecol,
                               const float* __restrict__ ea, const float* __restrict__ dis,
                               int* __restrict__ cursor,
                               half8_t* __restrict__ eah, int* __restrict__ rows) {
    int e = blockIdx.x * 256 + threadIdx.x;
    int c = ecol[e];
    int r = erow[e];
    float nrm = dis[r] * dis[c];
    int pos = atomicAdd(&cursor[c], 1);
    const float* p = ea + (size_t)e * 7;
    half8_t v;
    v[0] = (_Float16)p[0]; v[1] = (_Float16)p[1]; v[2] = (_Float16)p[2];
    v[3] = (_Float16)p[3]; v[4] = (_Float16)p[4]; v[5] = (_Float16)p[5];
    v[6] = (_Float16)p[6]; v[7] = (_Float16)nrm;
    eah[pos] = v;
    rows[pos] = r;
}

// ================= xl = act(h) @ W + b  via MFMA f16 =================
__global__ __launch_bounds__(256) void gemm_xl(const _Float16* __restrict__ hsrc,
                                               const int* __restrict__ xidx,
                                               const float* __restrict__ nemb,
                                               const float* __restrict__ colsum_p,
                                               const float* __restrict__ colsumsq_p,
                                               const float* __restrict__ gamma_p,
                                               const float* __restrict__ beta_p,
                                               const float* __restrict__ Wl,
                                               const float* __restrict__ bl,
                                               _Float16* __restrict__ xlo, int mode) {
    __shared__ half8_t sB[2048];          // [ct][ks][lane] fragments, 32 KB
    __shared__ float sScale[H], sShift[H];
    int t = threadIdx.x;
    if (mode == 1 && t < H) {
        float mean = colsum_p[t] * (1.0f / N_NODES);
        float var = colsumsq_p[t] * (1.0f / N_NODES) - mean * mean;
        float s = gamma_p[t] * rsqrtf(var + BN_EPS);
        sScale[t] = s;
        sShift[t] = beta_p[t] - mean * s;
    }
    // stage W as B-fragments
    for (int idx = t; idx < 2048; idx += 256) {
        int ct = idx >> 8;
        int ks = (idx >> 6) & 3;
        int ln = idx & 63;
        int kbase = ks * 32 + (ln >> 4) * 8;
        int c = ct * 16 + (ln & 15);
        half8_t v;
#pragma unroll
        for (int i = 0; i < 8; i++)
            v[i] = (_Float16)Wl[(size_t)(kbase + i) * H + c];
        sB[idx] = v;
    }
    __syncthreads();

    int w = t >> 6, lane = t & 63;
    int lq = lane >> 4, lr = lane & 15;
    int rbase = blockIdx.x * 128 + w * 32;

    floatx4 acc[2][8];
#pragma unroll
    for (int rt = 0; rt < 2; rt++)
#pragma unroll
        for (int ct = 0; ct < 8; ct++) acc[rt][ct] = (floatx4)0.0f;

    float bias[8];
#pragma unroll
    for (int ct = 0; ct < 8; ct++) bias[ct] = bl[ct * 16 + lr];

    int arow[2], xv[2];
#pragma unroll
    for (int rt = 0; rt < 2; rt++) {
        int row = rbase + rt * 16 + lr;
        if (row > N_NODES - 1) row = N_NODES - 1;
        arow[rt] = row;
        if (mode == 0) xv[rt] = xidx[row];
    }

    for (int ks = 0; ks < 4; ks++) {
        int k0 = ks * 32 + lq * 8;
        half8_t a[2];
#pragma unroll
        for (int rt = 0; rt < 2; rt++) {
            float f[8];
            if (mode == 0) {
                const float* p = nemb + (size_t)xv[rt] * H + k0;
                float4 u0 = *(const float4*)p;
                float4 u1 = *(const float4*)(p + 4);
                f[0] = u0.x; f[1] = u0.y; f[2] = u0.z; f[3] = u0.w;
                f[4] = u1.x; f[5] = u1.y; f[6] = u1.z; f[7] = u1.w;
            } else {
                half8_t u = *(const half8_t*)(hsrc + (size_t)arow[rt] * H + k0);
#pragma unroll
                for (int i = 0; i < 8; i++)
                    f[i] = frelu((float)u[i] * sScale[k0 + i] + sShift[k0 + i]);
            }
            half8_t av;
#pragma unroll
            for (int i = 0; i < 8; i++) av[i] = (_Float16)f[i];
            a[rt] = av;
        }
#pragma unroll
        for (int ct = 0; ct < 8; ct++) {
            half8_t bf = sB[(ct * 4 + ks) * 64 + lane];
            acc[0][ct] = __builtin_amdgcn_mfma_f32_16x16x32_f16(a[0], bf, acc[0][ct], 0, 0, 0);
            acc[1][ct] = __builtin_amdgcn_mfma_f32_16x16x32_f16(a[1], bf, acc[1][ct], 0, 0, 0);
        }
    }

    // cached stores: agg gathers xl right after — keep it in L2
#pragma unroll
    for (int rt = 0; rt < 2; rt++)
#pragma unroll
        for (int ct = 0; ct < 8; ct++)
#pragma unroll
            for (int r = 0; r < 4; r++) {
                int row = rbase + rt * 16 + lq * 4 + r;
                if (row < N_NODES)
                    xlo[(size_t)row * H + ct * 16 + lr] =
                        (_Float16)(acc[rt][ct][r] + bias[ct]);
            }
}

// ================= gather aggregation + BN stats =================
// wave per node (strided); lane owns cols {2*lane, 2*lane+1}; xl gathered as
// h2_t (cached); payload NT-loads only. MLP packed fp16, fp32 norm-accumulate.
__global__ __launch_bounds__(256) void agg_kernel(
    const int* __restrict__ rowptr, const half8_t* __restrict__ eah,
    const int* __restrict__ rows, const h2_t* __restrict__ xld,
    const float* __restrict__ invdeg, const float* __restrict__ rootl,
    const float* __restrict__ Wel, const float* __restrict__ bel,
    h2_t* __restrict__ hpd, float* __restrict__ colsum,
    float* __restrict__ colsumsq) {
    int t = threadIdx.x;
    int lane = t & 63, wv = t >> 6;
    int c0 = lane * 2;
    h2_t W20, W21, W22, W23, W24, W25, W26, be2;
    W20[0] = (_Float16)Wel[0 * H + c0]; W20[1] = (_Float16)Wel[0 * H + c0 + 1];
    W21[0] = (_Float16)Wel[1 * H + c0]; W21[1] = (_Float16)Wel[1 * H + c0 + 1];
    W22[0] = (_Float16)Wel[2 * H + c0]; W22[1] = (_Float16)Wel[2 * H + c0 + 1];
    W23[0] = (_Float16)Wel[3 * H + c0]; W23[1] = (_Float16)Wel[3 * H + c0 + 1];
    W24[0] = (_Float16)Wel[4 * H + c0]; W24[1] = (_Float16)Wel[4 * H + c0 + 1];
    W25[0] = (_Float16)Wel[5 * H + c0]; W25[1] = (_Float16)Wel[5 * H + c0 + 1];
    W26[0] = (_Float16)Wel[6 * H + c0]; W26[1] = (_Float16)Wel[6 * H + c0 + 1];
    be2[0] = (_Float16)bel[c0]; be2[1] = (_Float16)bel[c0 + 1];
    h2_t zero2;
    zero2[0] = (_Float16)0.0f; zero2[1] = (_Float16)0.0f;
    float rt0 = rootl[c0], rt1 = rootl[c0 + 1];
    float s0 = 0, s1 = 0, q0 = 0, q1 = 0;

#define MLP_BODY(PV, XG)                                                     \
    {                                                                        \
        h2_t m_ = be2;                                                       \
        m_ += (PV)[0] * W20;                                                 \
        m_ += (PV)[1] * W21;                                                 \
        m_ += (PV)[2] * W22;                                                 \
        m_ += (PV)[3] * W23;                                                 \
        m_ += (PV)[4] * W24;                                                 \
        m_ += (PV)[5] * W25;                                                 \
        m_ += (PV)[6] * W26;                                                 \
        h2_t sm_ = __builtin_elementwise_max((XG) + m_, zero2);              \
        float nrm_ = (float)(PV)[7];                                         \
        a0 = fmaf((float)sm_[0], nrm_, a0);                                  \
        a1 = fmaf((float)sm_[1], nrm_, a1);                                  \
    }

    for (int n_ = blockIdx.x * 4 + wv; n_ < N_NODES; n_ += gridDim.x * 4) {
        int n = __builtin_amdgcn_readfirstlane(n_);
        int jb = __builtin_amdgcn_readfirstlane(rowptr[n]);
        int je = __builtin_amdgcn_readfirstlane(rowptr[n + 1]);
        float a0 = 0, a1 = 0;
        int j = jb;
        for (; j + 16 <= je; j += 16) {
            int rr[16];
#pragma unroll
            for (int i = 0; i < 16; i++) rr[i] = rows[j + i];
            h2_t g[16];
#pragma unroll
            for (int i = 0; i < 16; i++) g[i] = xld[(size_t)rr[i] * 64 + lane];
#pragma unroll
            for (int i = 0; i < 16; i++) {
                half8_t pv = __builtin_nontemporal_load(&eah[j + i]);
                MLP_BODY(pv, g[i]);
            }
        }
        if (j + 8 <= je) {
            int rr[8];
#pragma unroll
            for (int i = 0; i < 8; i++) rr[i] = rows[j + i];
            h2_t g[8];
#pragma unroll
            for (int i = 0; i < 8; i++) g[i] = xld[(size_t)rr[i] * 64 + lane];
#pragma unroll
            for (int i = 0; i < 8; i++) {
                half8_t pv = __builtin_nontemporal_load(&eah[j + i]);
                MLP_BODY(pv, g[i]);
            }
            j += 8;
        }
        if (j + 4 <= je) {
            int rr[4];
#pragma unroll
            for (int i = 0; i < 4; i++) rr[i] = rows[j + i];
            h2_t g[4];
#pragma unroll
            for (int i = 0; i < 4; i++) g[i] = xld[(size_t)rr[i] * 64 + lane];
#pragma unroll
            for (int i = 0; i < 4; i++) {
                half8_t pv = __builtin_nontemporal_load(&eah[j + i]);
                MLP_BODY(pv, g[i]);
            }
            j += 4;
        }
        for (; j < je; j++) {
            int r_ = rows[j];
            h2_t g_ = xld[(size_t)r_ * 64 + lane];
            half8_t pv = __builtin_nontemporal_load(&eah[j]);
            MLP_BODY(pv, g_);
        }
        h2_t xn2 = xld[(size_t)n * 64 + lane];
        float id = invdeg[n];
        float p0 = a0 + frelu((float)xn2[0] + rt0) * id;
        float p1 = a1 + frelu((float)xn2[1] + rt1) * id;
        h2_t hp;
        hp[0] = (_Float16)p0; hp[1] = (_Float16)p1;
        hpd[(size_t)n * 64 + lane] = hp;
        s0 += p0; s1 += p1;
        q0 = fmaf(p0, p0, q0); q1 = fmaf(p1, p1, q1);
    }
#undef MLP_BODY

    __shared__ float red[4][H];
    red[wv][c0] = s0; red[wv][c0 + 1] = s1;
    __syncthreads();
    if (wv == 0) {
        float t0 = red[0][c0] + red[1][c0] + red[2][c0] + red[3][c0];
        float t1 = red[0][c0 + 1] + red[1][c0 + 1] + red[2][c0 + 1] + red[3][c0 + 1];
        unsafeAtomicAdd(&colsum[c0], t0);
        unsafeAtomicAdd(&colsum[c0 + 1], t1);
    }
    __syncthreads();
    red[wv][c0] = q0; red[wv][c0 + 1] = q1;
    __syncthreads();
    if (wv == 0) {
        float t0 = red[0][c0] + red[1][c0] + red[2][c0] + red[3][c0];
        float t1 = red[0][c0 + 1] + red[1][c0 + 1] + red[2][c0 + 1] + red[3][c0 + 1];
        unsafeAtomicAdd(&colsumsq[c0], t0);
        unsafeAtomicAdd(&colsumsq[c0 + 1], t1);
    }
}

// ================= pool (applies final BN in-kernel, fp16 input) =================
__global__ __launch_bounds__(256) void pool_kernel(const h2_t* __restrict__ hh,
                                                   const int* __restrict__ batch,
                                                   const float* __restrict__ colsum_p,
                                                   const float* __restrict__ colsumsq_p,
                                                   const float* __restrict__ gamma_p,
                                                   const float* __restrict__ beta_p,
                                                   float* __restrict__ pooled,
                                                   float* __restrict__ cnt) {
    __shared__ float sScale[H], sShift[H];
    int t = threadIdx.x;
    if (t < H) {
        float mean = colsum_p[t] * (1.0f / N_NODES);
        float var = colsumsq_p[t] * (1.0f / N_NODES) - mean * mean;
        float s = gamma_p[t] * rsqrtf(var + BN_EPS);
        sScale[t] = s;
        sShift[t] = beta_p[t] - mean * s;
    }
    __syncthreads();
    int cg = t & 63, rg = t >> 6;
    int c0 = cg * 2;
    float sc0 = sScale[c0], sc1 = sScale[c0 + 1];
    float sh0 = sShift[c0], sh1 = sShift[c0 + 1];
    int per = (N_NODES + gridDim.x - 1) / gridDim.x;
    int rstart = blockIdx.x * per;
    int rend = min(rstart + per, N_NODES);
    float a0 = 0, a1 = 0, runc = 0.0f;
    int cur = -1;
    for (int rowi = rstart + rg; rowi < rend; rowi += 4) {
        int g = batch[rowi];
        if (g != cur) {
            if (cur >= 0) {
                unsafeAtomicAdd(&pooled[(size_t)cur * H + c0 + 0], a0);
                unsafeAtomicAdd(&pooled[(size_t)cur * H + c0 + 1], a1);
                if (cg == 0) unsafeAtomicAdd(&cnt[cur], runc);
            }
            cur = g; a0 = 0; a1 = 0; runc = 0.0f;
        }
        h2_t v = hh[(size_t)rowi * 64 + cg];
        a0 += (float)v[0] * sc0 + sh0;
        a1 += (float)v[1] * sc1 + sh1;
        runc += 1.0f;
    }
    if (cur >= 0) {
        unsafeAtomicAdd(&pooled[(size_t)cur * H + c0 + 0], a0);
        unsafeAtomicAdd(&pooled[(size_t)cur * H + c0 + 1], a1);
        if (cg == 0) unsafeAtomicAdd(&cnt[cur], runc);
    }
}

__global__ __launch_bounds__(128) void final_gemm(const float* __restrict__ pooled,
                                                  const float* __restrict__ cnt,
                                                  const float* __restrict__ Wout,
                                                  const float* __restrict__ bout,
                                                  float* __restrict__ out) {
    __shared__ float sh[H];
    int g = blockIdx.x;
    int o = threadIdx.x;
    float c = fmaxf(cnt[g], 1.0f);
    sh[o] = pooled[(size_t)g * H + o] / c;
    __syncthreads();
    float acc = bout[o];
#pragma unroll 8
    for (int k = 0; k < H; k++) acc += sh[k] * Wout[(size_t)k * OUT_F + o];
    out[(size_t)g * OUT_F + o] = acc;
}

extern "C" void kernel_launch(void* const* d_in, const int* in_sizes, int n_in,
                              void* d_out, int out_size, void* d_ws, size_t ws_size,
                              hipStream_t stream) {
    const int*   x     = (const int*)d_in[0];
    const int*   ei    = (const int*)d_in[1];
    const float* ea    = (const float*)d_in[2];
    const int*   batch = (const int*)d_in[3];
    const float* nemb  = (const float*)d_in[4];
    const float* W     = (const float*)d_in[5];
    const float* b     = (const float*)d_in[6];
    const float* We    = (const float*)d_in[7];
    const float* be    = (const float*)d_in[8];
    const float* root  = (const float*)d_in[9];
    const float* gamma = (const float*)d_in[10];
    const float* beta  = (const float*)d_in[11];
    const float* Wout  = (const float*)d_in[12];
    const float* bout  = (const float*)d_in[13];
    float* out = (float*)d_out;

    const int* erow = ei;
    const int* ecol = ei + N_EDGES;

    float* ws = (float*)d_ws;
    size_t NH = (size_t)N_NODES * H;
    half8_t* eah  = (half8_t*)ws;                        // E half8 (fp16 payload)
    int*   rows   = (int*)(eah + N_EDGES);               // E ints
    float* hslot  = (float*)(rows + N_EDGES);            // NH/2 floats (fp16 hpre)
    _Float16* hpreh = (_Float16*)hslot;
    float* xslot  = hslot + NH / 2;                      // NH/2 floats (fp16 xl)
    _Float16* xlh = (_Float16*)xslot;
    int*   rowptr = (int*)(xslot + NH / 2);              // N+1 (+pad)
    float* dis    = (float*)(rowptr + N_NODES + 4);
    float* invdeg = dis + N_NODES;
    float* colsumAll = invdeg + N_NODES;                 // L*2*H floats
    float* pooled   = colsumAll + (size_t)L_LAYERS * 2 * H;
    float* cnt      = pooled + (size_t)G_GRAPHS * H;
    int*   blocksum = (int*)(cnt + G_GRAPHS);            // 128
    int*   blockoff = blocksum + 128;                    // 128

    // preprocessing temps alias into hpre region (hpre first written in layer 0 agg)
    int* degcnt = (int*)hslot;
    int* hist   = degcnt + N_NODES;
    int* cursor = hist + N_NODES;

    hipMemsetAsync(degcnt, 0, 2 * N_NODES * sizeof(int), stream);
    hipMemsetAsync(colsumAll, 0, (size_t)L_LAYERS * 2 * H * sizeof(float), stream);
    hipLaunchKernelGGL(count_kernel, dim3(N_EDGES / 256), dim3(256), 0, stream,
                       erow, ecol, degcnt, hist);
    hipLaunchKernelGGL(finish_deg, dim3((N_NODES + 255) / 256), dim3(256), 0, stream,
                       degcnt, dis, invdeg);
    hipLaunchKernelGGL(scan_part, dim3(SCAN_BLOCKS), dim3(1024), 0, stream,
                       hist, rowptr, blocksum);
    hipLaunchKernelGGL(scan_block, dim3(1), dim3(128), 0, stream,
                       blocksum, blockoff, rowptr);
    hipLaunchKernelGGL(scan_add, dim3(SCAN_BLOCKS), dim3(1024), 0, stream,
                       rowptr, blockoff, cursor);
    hipLaunchKernelGGL(scatter_kernel, dim3(N_EDGES / 256), dim3(256), 0, stream,
                       erow, ecol, ea, dis, cursor, eah, rows);

    for (int l = 0; l < L_LAYERS; l++) {
        const float* cs_prev = colsumAll + (size_t)(l - 1) * 2 * H;  // unused when l==0
        hipLaunchKernelGGL(gemm_xl, dim3((N_NODES + 127) / 128), dim3(256), 0, stream,
                           hpreh, x, nemb,
                           (l == 0) ? colsumAll : cs_prev,
                           (l == 0) ? colsumAll : cs_prev + H,
                           gamma + (size_t)(l ? l - 1 : 0) * H,
                           beta + (size_t)(l ? l - 1 : 0) * H,
                           W + (size_t)l * H * H, b + (size_t)l * H, xlh,
                           (l == 0) ? 0 : 1);
        float* cs = colsumAll + (size_t)l * 2 * H;
        hipLaunchKernelGGL(agg_kernel, dim3(2048), dim3(256), 0, stream,
                           rowptr, eah, rows, (const h2_t*)xlh, invdeg,
                           root + (size_t)l * H, We + (size_t)l * 7 * H, be + (size_t)l * H,
                           (h2_t*)hpreh, cs, cs + H);
    }

    hipMemsetAsync(pooled, 0, ((size_t)G_GRAPHS * H + G_GRAPHS) * sizeof(float), stream);
    {
        const float* cs4 = colsumAll + (size_t)(L_LAYERS - 1) * 2 * H;
        hipLaunchKernelGGL(pool_kernel, dim3(256), dim3(256), 0, stream,
                           (const h2_t*)hpreh, batch, cs4, cs4 + H,
                           gamma + (size_t)(L_LAYERS - 1) * H,
                           beta + (size_t)(L_LAYERS - 1) * H, pooled, cnt);
    }
    hipLaunchKernelGGL(final_gemm, dim3(G_GRAPHS), dim3(OUT_F), 0, stream,
                       pooled, cnt, Wout, bout, out);
}